// Round 14
// baseline (2354.463 us; speedup 1.0000x reference)
//
#include <hip/hip_runtime.h>

typedef short bf16x8 __attribute__((ext_vector_type(8)));
typedef float f32x4 __attribute__((ext_vector_type(4)));
typedef unsigned int u32x2 __attribute__((ext_vector_type(2)));
typedef unsigned int u32x4 __attribute__((ext_vector_type(4)));
typedef unsigned long long u64x2 __attribute__((ext_vector_type(2)));

__device__ __forceinline__ unsigned short f2bf(float f) {
  unsigned u = __float_as_uint(f);
  unsigned r = (u + 0x7FFFu + ((u >> 16) & 1u)) >> 16;
  return (unsigned short)r;
}
__device__ __forceinline__ float bf2f(unsigned short s) {
  return __uint_as_float(((unsigned)s) << 16);
}
__device__ __forceinline__ float sigm(float x) {
  return __builtin_amdgcn_rcpf(1.f + __expf(-x));
}
__device__ __forceinline__ float tanh_a(float x) {
  return 1.f - 2.f * __builtin_amdgcn_rcpf(__expf(2.f * x) + 1.f);
}

__device__ __forceinline__ void gload_lds16(const void* g, void* l) {
  __builtin_amdgcn_global_load_lds(
      (const __attribute__((address_space(1))) unsigned int*)g,
      (__attribute__((address_space(3))) unsigned int*)l, 16, 0, 0);
}

#define ALOAD(p)     __hip_atomic_load((p), __ATOMIC_RELAXED, __HIP_MEMORY_SCOPE_AGENT)
#define ASTORE(p, v) __hip_atomic_store((p), (v), __ATOMIC_RELAXED, __HIP_MEMORY_SCOPE_AGENT)

// ---------------- pack kernels ----------------

// x [b][t][1024] fp32 -> xbt [t][b][1024] bf16 (t-major: a t's A-tile is contiguous 128 KB)
__global__ void k_cvt_x(const float* __restrict__ x, unsigned short* __restrict__ xbt) {
  int idx = blockIdx.x * 256 + threadIdx.x;      // 0 .. 4194303 (64*512*128)
  int i8 = idx & 127;
  int t  = (idx >> 7) & 511;
  int b  = idx >> 16;
  const float4* src = (const float4*)(x + ((size_t)(b * 512 + t) * 1024 + i8 * 8));
  float4 v0 = src[0], v1 = src[1];
  ushort4 o0, o1;
  o0.x = f2bf(v0.x); o0.y = f2bf(v0.y); o0.z = f2bf(v0.z); o0.w = f2bf(v0.w);
  o1.x = f2bf(v1.x); o1.y = f2bf(v1.y); o1.z = f2bf(v1.z); o1.w = f2bf(v1.w);
  ushort4* dst = (ushort4*)(xbt + ((size_t)(t * 64 + b) * 1024 + i8 * 8));
  dst[0] = o0; dst[1] = o1;
}

// transpose 1024x1024 fp32 -> bf16; BOTH wx and wh slabs packed in permuted-row order
// row = (j>>2)*16 + gate*4 + (j&3)
__global__ void k_pack_w(const float* __restrict__ wxi, const float* __restrict__ wxf,
                         const float* __restrict__ wxg, const float* __restrict__ wxo,
                         const float* __restrict__ whi, const float* __restrict__ whf,
                         const float* __restrict__ whg, const float* __restrict__ who,
                         unsigned short* __restrict__ wxtp, unsigned short* __restrict__ whp) {
  const float* srcs[8] = {wxi, wxf, wxg, wxo, whi, whf, whg, who};
  int slab = blockIdx.z;
  const float* src = srcs[slab];
  int gate = slab & 3;
  bool is_wh = slab >= 4;
  __shared__ float tile[32][33];
  int tx = threadIdx.x, ty = threadIdx.y;
  int j0 = blockIdx.x * 32, k0 = blockIdx.y * 32;
  #pragma unroll
  for (int i = 0; i < 32; i += 8)
    tile[ty + i][tx] = src[(size_t)(k0 + ty + i) * 1024 + j0 + tx];
  __syncthreads();
  unsigned short* dst = is_wh ? whp : wxtp;
  #pragma unroll
  for (int i = 0; i < 32; i += 8) {
    int j = j0 + ty + i;
    int k = k0 + tx;
    float v = tile[tx][ty + i];
    int row = (j >> 2) * 16 + gate * 4 + (j & 3);
    dst[(size_t)row * 1024 + k] = f2bf(v);
  }
}

__global__ void k_bias(const float* bxi, const float* bhi, const float* bxf, const float* bhf,
                       const float* bxg, const float* bhg, const float* bxo, const float* bho,
                       float* __restrict__ pbx4) {
  int n = blockIdx.x * 256 + threadIdx.x;  // 0..4095
  int gate = n >> 10, j = n & 1023;
  const float* a = gate == 0 ? bxi : gate == 1 ? bxf : gate == 2 ? bxg : bxo;
  const float* b = gate == 0 ? bhi : gate == 1 ? bhf : gate == 2 ? bhg : bho;
  int pcol = (j >> 2) * 16 + gate * 4 + (j & 3);
  pbx4[pcol] = a[j] + b[j];
}

// init flags ONLY (hbuf is zeroed in-kernel by each group through its own sc0/L2 path;
// touching hbuf here would create competing dirty copies in other XCDs' L2s).
__global__ void k_init(unsigned int* __restrict__ flags, unsigned int* __restrict__ xflags) {
  int i = blockIdx.x * 256 + threadIdx.x;  // 0..32767
  if (i < 128) ASTORE(flags + i, 0u);
  if (i < 16384) ASTORE(xflags + i, 0u);
}

// ---------------- fused cooperative kernel: 256 blocks x 512 threads ----------------
// Role by XCD (default dispatch: XCD = bid & 7):
//   bid&7 in {0..3}: recurrence group q = bid&7 (all 32 blocks of a group on ONE XCD
//                    -> h exchange via sc0-only ops stays in that XCD's L2).
//   bid&7 in {4..7}: xproj producer, strip s = bid>>3, phase = (bid&7)-4.
// Flags remain agent-scope (L3-coherent) so a wrong placement can only produce stale
// h values (caught by validation), never a deadlock.
// Flag numbering: k_init=0; init-zero round publishes 1; end of step t publishes t+2.

__global__ __launch_bounds__(512, 1) void k_fused(
    const unsigned short* __restrict__ xbt,   // [512][64][1024] bf16 (t-major)
    const unsigned short* __restrict__ wxtp,  // [4096][1024] bf16, permuted rows
    const unsigned short* __restrict__ whp,   // [4096][1024] bf16, permuted rows
    const float* __restrict__ pbx4,           // [4096] permuted
    unsigned short* __restrict__ xp,          // [512][4096][64] bf16
    unsigned short* __restrict__ hbuf,        // [2][64][1024] bf16 (XCD-local traffic)
    unsigned int* __restrict__ flags,         // [128] h-flags (L3)
    unsigned int* __restrict__ xflags,        // [512][32] xp-flags (L3)
    float* __restrict__ out)                  // h (65536) then c (65536), fp32
{
  __shared__ __align__(16) short smem[16 * 1032];  // 33 KB, shared by both roles
  const int bid = blockIdx.x;
  const int tid = threadIdx.x;
  const int lane = tid & 63, w = tid >> 6;     // 8 waves
  const int l15 = lane & 15, hi = lane >> 4;
  const int xcd = bid & 7;

  if (xcd >= 4) {
    // ================= xproj producer =================
    const int s = bid >> 3, ph = xcd - 4;      // strip 0..31, phase 0..3
    short* As = smem;                          // [64 rows][512 B] per K-chunk, XOR-swizzled
    const char* xbB = (const char*)xbt;
    const unsigned short* wrowx = wxtp + (size_t)((8 * s + w) * 16 + l15) * 1024 + hi * 8;
    bf16x8 wfx[32];
    #pragma unroll
    for (int ks = 0; ks < 32; ++ks) wfx[ks] = *(const bf16x8*)(wrowx + ks * 32);
    const int pcg = (8 * s + w) * 16 + l15;
    const float bias = pbx4[pcg];

    for (int t = ph; t < 512; t += 4) {
      f32x4 acc[4] = {};
      for (int kc = 0; kc < 4; ++kc) {
        #pragma unroll
        for (int p = 0; p < 4; ++p) {
          int d = p * 8192 + tid * 16;
          int r = d >> 9;
          int inner = d & 511;
          int swz = (inner & 127) ^ ((r & 7) << 4);
          gload_lds16(xbB + ((size_t)(t * 64 + r) * 2048 + kc * 512 + (inner & ~127) + swz),
                      (char*)As + d);
        }
        asm volatile("s_waitcnt vmcnt(0)" ::: "memory");
        __syncthreads();
        #pragma unroll
        for (int ksl = 0; ksl < 8; ++ksl) {
          bf16x8 bfr = wfx[kc * 8 + ksl];
          #pragma unroll
          for (int mt = 0; mt < 4; ++mt) {
            int r = mt * 16 + l15;
            int cb = ksl * 64 + hi * 16;
            int byt = r * 512 + (cb & ~127) + ((cb & 127) ^ ((r & 7) << 4));
            bf16x8 afr = *(const bf16x8*)((const char*)As + byt);
            acc[mt] = __builtin_amdgcn_mfma_f32_16x16x32_bf16(afr, bfr, acc[mt], 0, 0, 0);
          }
        }
        __syncthreads();
      }
      #pragma unroll
      for (int mt = 0; mt < 4; ++mt) {
        unsigned h0 = f2bf(acc[mt][0] + bias), h1 = f2bf(acc[mt][1] + bias);
        unsigned h2 = f2bf(acc[mt][2] + bias), h3 = f2bf(acc[mt][3] + bias);
        unsigned long long pv = (unsigned long long)(h0 | (h1 << 16)) |
                                ((unsigned long long)(h2 | (h3 << 16)) << 32);
        size_t ei = ((size_t)t * 4096 + pcg) * 16 + mt * 4 + hi;  // ull index
        ASTORE((unsigned long long*)xp + ei, pv);
      }
      __syncthreads();  // drains all waves' stores before flag
      if (tid == 0) ASTORE(xflags + t * 32 + s, 1u);
    }
    return;
  }

  // ================= recurrence (R8 structure, XCD-local h exchange) =================
  const int q = xcd;              // batch group (0..3) == XCD
  const int cg = bid >> 3;        // column group (0..31)
  const int r0 = q * 16;          // first batch row
  const int gate = l15 >> 2, jj = l15 & 3;
  short* hs = smem;               // 16 h-rows, padded stride 1032

  const unsigned short* wrow = whp + (size_t)((8 * cg + w) * 16 + l15) * 1024 + hi * 8;
  bf16x8 wf[32];
  #pragma unroll
  for (int ks = 0; ks < 32; ++ks) wf[ks] = *(const bf16x8*)(wrow + ks * 32);

  const int hcol = 32 * cg + 4 * w + jj;
  const int pc = (8 * cg + w) * 16 + l15;  // permuted xp col for this lane (strip cg)
  const int base = (lane & 48) | jj;       // gate-gather source
  const int pbase = lane & 48;             // h-pack gather source
  const int srow = tid >> 5;               // stage: h-row (0..15)
  const int scp = tid & 31;                // stage: chunk position (0..31)
  float cst[4] = {0.f, 0.f, 0.f, 0.f};

  // --- init round: zero OWN h slice (both buffers) through sc0 (this XCD's L2),
  // overwriting any stale dirty lines from a previous replay; publish flag=1.
  if (tid < 256) {
    int buf = tid >> 7, r = (tid >> 3) & 15, cq = tid & 7;
    unsigned short* zp = hbuf + buf * 65536 + (r0 + r) * 1024 + 32 * cg + cq * 4;
    unsigned long long zv = 0ull;
    asm volatile("global_store_dwordx2 %0, %1, off sc0" :: "v"(zp), "v"(zv) : "memory");
  }
  __syncthreads();  // drains zero-stores
  if (tid == 0) ASTORE(flags + q * 32 + cg, 1u);
  {
    const unsigned int* fp = flags + q * 32 + (lane & 31);
    while (true) {
      unsigned f = ALOAD(fp);
      if (__all(f >= 1u)) break;
    }
  }

  // initial xpv (t=0): wait for producer strip cg, then one 8B sc-load
  while (ALOAD(xflags + cg) == 0) {}
  u32x2 nf;
  asm volatile("global_load_dwordx2 %0, %1, off sc0 sc1"
               : "=v"(nf) : "v"((const char*)xp + ((size_t)pc * 64 + r0 + hi * 4) * 2) : "memory");
  asm volatile("s_waitcnt vmcnt(0)" ::: "memory");
  __builtin_amdgcn_sched_barrier(0);
  float xpv[4];
  xpv[0] = bf2f((unsigned short)(nf.x & 0xFFFFu));
  xpv[1] = bf2f((unsigned short)(nf.x >> 16));
  xpv[2] = bf2f((unsigned short)(nf.y & 0xFFFFu));
  xpv[3] = bf2f((unsigned short)(nf.y >> 16));

  for (int t = 0; t < 512; ++t) {
    // --- stage this group's 16 h-rows into LDS (sc0: XCD-local L2 reads)
    {
      const char* gsrc = (const char*)(hbuf + (t & 1) * 65536 + (r0 + srow) * 1024) + scp * 16;
      u64x2 tmp[4];
      #pragma unroll
      for (int i = 0; i < 4; ++i)
        asm volatile("global_load_dwordx4 %0, %1, off sc0"
                     : "=v"(tmp[i]) : "v"(gsrc + i * 512) : "memory");
      asm volatile("s_waitcnt vmcnt(0)" ::: "memory");
      __builtin_amdgcn_sched_barrier(0);
      short* ld = hs + srow * 1032 + scp * 8;
      #pragma unroll
      for (int i = 0; i < 4; ++i)
        *(bf16x8*)(ld + i * 256) = __builtin_bit_cast(bf16x8, tmp[i]);
    }
    __syncthreads();

    // --- GEMM from LDS: 32 ds_read_b128 + 32 MFMA, 4 chained accumulators
    const short* hsrow = hs + l15 * 1032 + hi * 8;
    f32x4 ac0 = {}, ac1 = {}, ac2 = {}, ac3 = {};
    #pragma unroll
    for (int ks = 0; ks < 32; ks += 4) {
      ac0 = __builtin_amdgcn_mfma_f32_16x16x32_bf16(*(const bf16x8*)(hsrow + ks * 32),       wf[ks],     ac0, 0, 0, 0);
      ac1 = __builtin_amdgcn_mfma_f32_16x16x32_bf16(*(const bf16x8*)(hsrow + (ks + 1) * 32), wf[ks + 1], ac1, 0, 0, 0);
      ac2 = __builtin_amdgcn_mfma_f32_16x16x32_bf16(*(const bf16x8*)(hsrow + (ks + 2) * 32), wf[ks + 2], ac2, 0, 0, 0);
      ac3 = __builtin_amdgcn_mfma_f32_16x16x32_bf16(*(const bf16x8*)(hsrow + (ks + 3) * 32), wf[ks + 3], ac3, 0, 0, 0);
    }
    f32x4 acc = (ac0 + ac1) + (ac2 + ac3);

    float act[4];
    #pragma unroll
    for (int ri = 0; ri < 4; ++ri) {
      float v = acc[ri] + xpv[ri];
      act[ri] = (gate == 2) ? tanh_a(v) : sigm(v);
    }
    float hv[4];
    #pragma unroll
    for (int ri = 0; ri < 4; ++ri) {
      float iv = __shfl(act[ri], base);
      float fv = __shfl(act[ri], base + 4);
      float gv = __shfl(act[ri], base + 8);
      float ov = __shfl(act[ri], base + 12);
      cst[ri] = fv * cst[ri] + iv * gv;
      hv[ri] = ov * tanh_a(cst[ri]);
    }

    if (t == 511) {
      if (gate == 0) {
        #pragma unroll
        for (int ri = 0; ri < 4; ++ri) {
          int b = r0 + hi * 4 + ri;
          out[b * 1024 + hcol] = hv[ri];
          out[65536 + b * 1024 + hcol] = cst[ri];
        }
      }
      break;
    }

    // --- pack 4 cols -> one 8B sc0 store per (hi,ri) row (stays in this XCD's L2)
    unsigned short* hn = hbuf + ((t + 1) & 1) * 65536;
    #pragma unroll
    for (int ri = 0; ri < 4; ++ri) {
      int hbv = (int)f2bf(hv[ri]);
      int c0 = __shfl(hbv, pbase + 0);
      int c1 = __shfl(hbv, pbase + 1);
      int c2 = __shfl(hbv, pbase + 2);
      int c3 = __shfl(hbv, pbase + 3);
      if (l15 == 0) {
        unsigned lo = ((unsigned)c0 & 0xFFFFu) | ((unsigned)c1 << 16);
        unsigned long long hi64 = ((unsigned)c2 & 0xFFFFu) | ((unsigned)c3 << 16);
        unsigned long long pv = (unsigned long long)lo | (hi64 << 32);
        int row = r0 + hi * 4 + ri;
        unsigned short* sp = hn + row * 1024 + 32 * cg + 4 * w;
        asm volatile("global_store_dwordx2 %0, %1, off sc0" :: "v"(sp), "v"(pv) : "memory");
      }
    }

    // --- publish: syncthreads drains all waves' stores (vmcnt 0), then flag = t+2
    __syncthreads();
    if (tid == 0) ASTORE(flags + q * 32 + cg, (unsigned)(t + 2));

    // --- prefetch next step's xp under the poll shadow: strip flag, then 8B sc-load
    while (ALOAD(xflags + (t + 1) * 32 + cg) == 0) {}
    asm volatile("global_load_dwordx2 %0, %1, off sc0 sc1"
                 : "=v"(nf)
                 : "v"((const char*)xp + (((size_t)(t + 1) * 4096 + pc) * 64 + r0 + hi * 4) * 2)
                 : "memory");

    // --- wait: every wave polls this group's 32 h-flags (one 4B load/lane), target t+2
    {
      const unsigned int* fp = flags + q * 32 + (lane & 31);
      unsigned tgt = (unsigned)(t + 2);
      while (true) {
        unsigned f = ALOAD(fp);
        if (__all(f >= tgt)) break;
      }
    }
    asm volatile("s_waitcnt vmcnt(0)" ::: "memory");
    __builtin_amdgcn_sched_barrier(0);
    xpv[0] = bf2f((unsigned short)(nf.x & 0xFFFFu));
    xpv[1] = bf2f((unsigned short)(nf.x >> 16));
    xpv[2] = bf2f((unsigned short)(nf.y & 0xFFFFu));
    xpv[3] = bf2f((unsigned short)(nf.y >> 16));
  }
}

// ---------------- host ----------------

extern "C" void kernel_launch(void* const* d_in, const int* in_sizes, int n_in,
                              void* d_out, int out_size, void* d_ws, size_t ws_size,
                              hipStream_t stream) {
  const float* x = (const float*)d_in[0];
  const float* wxi = (const float*)d_in[1];
  const float* whi = (const float*)d_in[2];
  const float* wxf = (const float*)d_in[3];
  const float* whf = (const float*)d_in[4];
  const float* wxg = (const float*)d_in[5];
  const float* whg = (const float*)d_in[6];
  const float* wxo = (const float*)d_in[7];
  const float* who = (const float*)d_in[8];

  char* ws = (char*)d_ws;
  unsigned short* xbt   = (unsigned short*)(ws);                    // 64 MiB [t][b][1024]
  unsigned short* wxtp  = (unsigned short*)(ws + 67108864);         // 8 MiB
  unsigned short* whp   = (unsigned short*)(ws + 75497472);         // 8 MiB
  unsigned short* xpj   = (unsigned short*)(ws + 83886080);         // 256 MiB [t][pc][b]
  float*          pbx4  = (float*)(ws + 352321536);                 // 16 KiB
  unsigned short* hbuf  = (unsigned short*)(ws + 352337920);        // 256 KiB
  unsigned int*   flags = (unsigned int*)(ws + 352600064);          // 512 B
  unsigned int*   xflags= (unsigned int*)(ws + 352604160);          // 64 KiB

  k_cvt_x<<<16384, 256, 0, stream>>>(x, xbt);
  k_pack_w<<<dim3(32, 32, 8), dim3(32, 8), 0, stream>>>(wxi, wxf, wxg, wxo, whi, whf, whg, who, wxtp, whp);
  k_bias<<<16, 256, 0, stream>>>((const float*)d_in[9], (const float*)d_in[10],
                                 (const float*)d_in[11], (const float*)d_in[12],
                                 (const float*)d_in[13], (const float*)d_in[14],
                                 (const float*)d_in[15], (const float*)d_in[16], pbx4);
  k_init<<<128, 256, 0, stream>>>(flags, xflags);

  float* out = (float*)d_out;
  void* args[] = {(void*)&xbt, (void*)&wxtp, (void*)&whp, (void*)&pbx4,
                  (void*)&xpj, (void*)&hbuf, (void*)&flags, (void*)&xflags, (void*)&out};
  hipLaunchCooperativeKernel((const void*)k_fused, dim3(256), dim3(512), args, 0, stream);
}

// Round 15
// 1928.069 us; speedup vs baseline: 1.2212x; 1.2212x over previous
//
#include <hip/hip_runtime.h>

typedef short bf16x8 __attribute__((ext_vector_type(8)));
typedef float f32x4 __attribute__((ext_vector_type(4)));
typedef unsigned int u32x2 __attribute__((ext_vector_type(2)));
typedef unsigned int u32x4 __attribute__((ext_vector_type(4)));
typedef unsigned long long u64x2 __attribute__((ext_vector_type(2)));

__device__ __forceinline__ unsigned short f2bf(float f) {
  unsigned u = __float_as_uint(f);
  unsigned r = (u + 0x7FFFu + ((u >> 16) & 1u)) >> 16;
  return (unsigned short)r;
}
__device__ __forceinline__ float bf2f(unsigned short s) {
  return __uint_as_float(((unsigned)s) << 16);
}
__device__ __forceinline__ float sigm(float x) {
  return __builtin_amdgcn_rcpf(1.f + __expf(-x));
}
__device__ __forceinline__ float tanh_a(float x) {
  return 1.f - 2.f * __builtin_amdgcn_rcpf(__expf(2.f * x) + 1.f);
}

__device__ __forceinline__ void gload_lds16(const void* g, void* l) {
  __builtin_amdgcn_global_load_lds(
      (const __attribute__((address_space(1))) unsigned int*)g,
      (__attribute__((address_space(3))) unsigned int*)l, 16, 0, 0);
}

#define ALOAD(p)     __hip_atomic_load((p), __ATOMIC_RELAXED, __HIP_MEMORY_SCOPE_AGENT)
#define ASTORE(p, v) __hip_atomic_store((p), (v), __ATOMIC_RELAXED, __HIP_MEMORY_SCOPE_AGENT)

// ---------------- pack kernels ----------------

// x [b][t][1024] fp32 -> xbt [t][b][1024] bf16 (t-major: a t's A-tile is contiguous 128 KB)
__global__ void k_cvt_x(const float* __restrict__ x, unsigned short* __restrict__ xbt) {
  int idx = blockIdx.x * 256 + threadIdx.x;      // 0 .. 4194303 (64*512*128)
  int i8 = idx & 127;
  int t  = (idx >> 7) & 511;
  int b  = idx >> 16;
  const float4* src = (const float4*)(x + ((size_t)(b * 512 + t) * 1024 + i8 * 8));
  float4 v0 = src[0], v1 = src[1];
  ushort4 o0, o1;
  o0.x = f2bf(v0.x); o0.y = f2bf(v0.y); o0.z = f2bf(v0.z); o0.w = f2bf(v0.w);
  o1.x = f2bf(v1.x); o1.y = f2bf(v1.y); o1.z = f2bf(v1.z); o1.w = f2bf(v1.w);
  ushort4* dst = (ushort4*)(xbt + ((size_t)(t * 64 + b) * 1024 + i8 * 8));
  dst[0] = o0; dst[1] = o1;
}

// transpose 1024x1024 fp32 -> bf16; BOTH wx and wh slabs packed in permuted-row order
// row = (j>>2)*16 + gate*4 + (j&3)
__global__ void k_pack_w(const float* __restrict__ wxi, const float* __restrict__ wxf,
                         const float* __restrict__ wxg, const float* __restrict__ wxo,
                         const float* __restrict__ whi, const float* __restrict__ whf,
                         const float* __restrict__ whg, const float* __restrict__ who,
                         unsigned short* __restrict__ wxtp, unsigned short* __restrict__ whp) {
  const float* srcs[8] = {wxi, wxf, wxg, wxo, whi, whf, whg, who};
  int slab = blockIdx.z;
  const float* src = srcs[slab];
  int gate = slab & 3;
  bool is_wh = slab >= 4;
  __shared__ float tile[32][33];
  int tx = threadIdx.x, ty = threadIdx.y;
  int j0 = blockIdx.x * 32, k0 = blockIdx.y * 32;
  #pragma unroll
  for (int i = 0; i < 32; i += 8)
    tile[ty + i][tx] = src[(size_t)(k0 + ty + i) * 1024 + j0 + tx];
  __syncthreads();
  unsigned short* dst = is_wh ? whp : wxtp;
  #pragma unroll
  for (int i = 0; i < 32; i += 8) {
    int j = j0 + ty + i;
    int k = k0 + tx;
    float v = tile[tx][ty + i];
    int row = (j >> 2) * 16 + gate * 4 + (j & 3);
    dst[(size_t)row * 1024 + k] = f2bf(v);
  }
}

__global__ void k_bias(const float* bxi, const float* bhi, const float* bxf, const float* bhf,
                       const float* bxg, const float* bhg, const float* bxo, const float* bho,
                       float* __restrict__ pbx4) {
  int n = blockIdx.x * 256 + threadIdx.x;  // 0..4095
  int gate = n >> 10, j = n & 1023;
  const float* a = gate == 0 ? bxi : gate == 1 ? bxf : gate == 2 ? bxg : bxo;
  const float* b = gate == 0 ? bhi : gate == 1 ? bhf : gate == 2 ? bhg : bho;
  int pcol = (j >> 2) * 16 + gate * 4 + (j & 3);
  pbx4[pcol] = a[j] + b[j];
}

// init recurrence state + flags through the SAME coherence path k_fused uses.
__global__ void k_init(unsigned short* __restrict__ hbuf, unsigned int* __restrict__ flags,
                       unsigned int* __restrict__ xflags) {
  int i = blockIdx.x * 256 + threadIdx.x;  // 0..32767
  ASTORE((unsigned long long*)hbuf + i, 0ull);
  if (i < 128) ASTORE(flags + i, 0u);
  if (i < 16384) ASTORE(xflags + i, 0u);
}

// ---------------- fused cooperative kernel: 256 blocks x 512 threads ----------------
// Blocks 0..127: recurrence (R8 structure). Blocks 128..255: xproj producers.
// Producer: 4 blocks per strip s; phase ph handles t = ph, ph+4, ... (per-strip rate =
// 4x one block). B-slice register-resident (wfx[32]); A read from t-major xbt in four
// 32 KB K-chunks through LDS (linear dest + XOR-preswizzled source). No throttle.
// xp stored [t][pc][b] via 8B agent atomics; xflags[t*32+s] after the draining barrier.

__global__ __launch_bounds__(512, 1) void k_fused(
    const unsigned short* __restrict__ xbt,   // [512][64][1024] bf16 (t-major)
    const unsigned short* __restrict__ wxtp,  // [4096][1024] bf16, permuted rows
    const unsigned short* __restrict__ whp,   // [4096][1024] bf16, permuted rows
    const float* __restrict__ pbx4,           // [4096] permuted
    unsigned short* __restrict__ xp,          // [512][4096][64] bf16
    unsigned short* __restrict__ hbuf,        // [2][64][1024] bf16
    unsigned int* __restrict__ flags,         // [128] h-flags
    unsigned int* __restrict__ xflags,        // [512][32] xp-flags
    float* __restrict__ out)                  // h (65536) then c (65536), fp32
{
  __shared__ __align__(16) short smem[16 * 1032];  // 33 KB, shared by both roles
  const int bid = blockIdx.x;
  const int tid = threadIdx.x;
  const int lane = tid & 63, w = tid >> 6;     // 8 waves
  const int l15 = lane & 15, hi = lane >> 4;

  if (bid >= 128) {
    // ================= xproj producer =================
    const int wid = bid - 128;
    const int s = wid >> 2, ph = wid & 3;      // strip 0..31, phase 0..3
    short* As = smem;                          // [64 rows][512 B] per K-chunk, XOR-swizzled
    const char* xbB = (const char*)xbt;
    // B strip in registers: wave w owns permuted cols (8s+w)*16 + l15, full K=1024
    const unsigned short* wrowx = wxtp + (size_t)((8 * s + w) * 16 + l15) * 1024 + hi * 8;
    bf16x8 wfx[32];
    #pragma unroll
    for (int ks = 0; ks < 32; ++ks) wfx[ks] = *(const bf16x8*)(wrowx + ks * 32);
    const int pcg = (8 * s + w) * 16 + l15;
    const float bias = pbx4[pcg];

    for (int t = ph; t < 512; t += 4) {
      f32x4 acc[4] = {};
      for (int kc = 0; kc < 4; ++kc) {
        #pragma unroll
        for (int p = 0; p < 4; ++p) {
          int d = p * 8192 + tid * 16;
          int r = d >> 9;
          int inner = d & 511;
          int swz = (inner & 127) ^ ((r & 7) << 4);
          gload_lds16(xbB + ((size_t)(t * 64 + r) * 2048 + kc * 512 + (inner & ~127) + swz),
                      (char*)As + d);
        }
        asm volatile("s_waitcnt vmcnt(0)" ::: "memory");
        __syncthreads();
        #pragma unroll
        for (int ksl = 0; ksl < 8; ++ksl) {
          bf16x8 bfr = wfx[kc * 8 + ksl];
          #pragma unroll
          for (int mt = 0; mt < 4; ++mt) {
            int r = mt * 16 + l15;
            int cb = ksl * 64 + hi * 16;
            int byt = r * 512 + (cb & ~127) + ((cb & 127) ^ ((r & 7) << 4));
            bf16x8 afr = *(const bf16x8*)((const char*)As + byt);
            acc[mt] = __builtin_amdgcn_mfma_f32_16x16x32_bf16(afr, bfr, acc[mt], 0, 0, 0);
          }
        }
        __syncthreads();
      }
      // epilogue: b = mt*16 + hi*4 + ri, col = pcg; layout [t][pc][b] -> 8B/frag
      #pragma unroll
      for (int mt = 0; mt < 4; ++mt) {
        unsigned h0 = f2bf(acc[mt][0] + bias), h1 = f2bf(acc[mt][1] + bias);
        unsigned h2 = f2bf(acc[mt][2] + bias), h3 = f2bf(acc[mt][3] + bias);
        unsigned long long pv = (unsigned long long)(h0 | (h1 << 16)) |
                                ((unsigned long long)(h2 | (h3 << 16)) << 32);
        size_t ei = ((size_t)t * 4096 + pcg) * 16 + mt * 4 + hi;  // ull index
        ASTORE((unsigned long long*)xp + ei, pv);
      }
      __syncthreads();  // every wave drains its own vmcnt before the barrier
      if (tid == 0) ASTORE(xflags + t * 32 + s, 1u);
    }
    return;
  }

  // ================= recurrence (R8 structure) =================
  const int q = bid >> 5;         // batch group (0..3)
  const int cg = bid & 31;        // column group (0..31)
  const int r0 = q * 16;          // first batch row
  const int gate = l15 >> 2, jj = l15 & 3;
  short* hs = smem;               // 16 h-rows, padded stride 1032

  // wh slice: wave w's 16 gate-cols = packed rows (8cg+w)*16 + l15
  const unsigned short* wrow = whp + (size_t)((8 * cg + w) * 16 + l15) * 1024 + hi * 8;
  bf16x8 wf[32];
  #pragma unroll
  for (int ks = 0; ks < 32; ++ks) wf[ks] = *(const bf16x8*)(wrow + ks * 32);

  const int hcol = 32 * cg + 4 * w + jj;
  const int pc = (8 * cg + w) * 16 + l15;  // permuted xp col for this lane (strip cg)
  const int base = (lane & 48) | jj;       // gate-gather source
  const int pbase = lane & 48;             // h-pack gather source
  const int srow = tid >> 5;               // stage: h-row (0..15)
  const int scp = tid & 31;                // stage: chunk position (0..31)
  float cst[4] = {0.f, 0.f, 0.f, 0.f};

  // initial xpv (t=0): wait for producer strip cg, then one 8B sc-load
  while (ALOAD(xflags + cg) == 0) {}
  u32x2 nf;
  asm volatile("global_load_dwordx2 %0, %1, off sc0 sc1"
               : "=v"(nf) : "v"((const char*)xp + ((size_t)pc * 64 + r0 + hi * 4) * 2) : "memory");
  asm volatile("s_waitcnt vmcnt(0)" ::: "memory");
  __builtin_amdgcn_sched_barrier(0);
  float xpv[4];
  xpv[0] = bf2f((unsigned short)(nf.x & 0xFFFFu));
  xpv[1] = bf2f((unsigned short)(nf.x >> 16));
  xpv[2] = bf2f((unsigned short)(nf.y & 0xFFFFu));
  xpv[3] = bf2f((unsigned short)(nf.y >> 16));

  for (int t = 0; t < 512; ++t) {
    // --- stage this group's 16 h-rows into LDS (coherent 16B bypass loads)
    {
      const char* gsrc = (const char*)(hbuf + (t & 1) * 65536 + (r0 + srow) * 1024) + scp * 16;
      u64x2 tmp[4];
      #pragma unroll
      for (int i = 0; i < 4; ++i)
        asm volatile("global_load_dwordx4 %0, %1, off sc0 sc1"
                     : "=v"(tmp[i]) : "v"(gsrc + i * 512) : "memory");
      asm volatile("s_waitcnt vmcnt(0)" ::: "memory");
      __builtin_amdgcn_sched_barrier(0);
      short* ld = hs + srow * 1032 + scp * 8;
      #pragma unroll
      for (int i = 0; i < 4; ++i)
        *(bf16x8*)(ld + i * 256) = __builtin_bit_cast(bf16x8, tmp[i]);
    }
    __syncthreads();

    // --- GEMM from LDS: 32 ds_read_b128 + 32 MFMA, 4 chained accumulators
    const short* hsrow = hs + l15 * 1032 + hi * 8;
    f32x4 ac0 = {}, ac1 = {}, ac2 = {}, ac3 = {};
    #pragma unroll
    for (int ks = 0; ks < 32; ks += 4) {
      ac0 = __builtin_amdgcn_mfma_f32_16x16x32_bf16(*(const bf16x8*)(hsrow + ks * 32),       wf[ks],     ac0, 0, 0, 0);
      ac1 = __builtin_amdgcn_mfma_f32_16x16x32_bf16(*(const bf16x8*)(hsrow + (ks + 1) * 32), wf[ks + 1], ac1, 0, 0, 0);
      ac2 = __builtin_amdgcn_mfma_f32_16x16x32_bf16(*(const bf16x8*)(hsrow + (ks + 2) * 32), wf[ks + 2], ac2, 0, 0, 0);
      ac3 = __builtin_amdgcn_mfma_f32_16x16x32_bf16(*(const bf16x8*)(hsrow + (ks + 3) * 32), wf[ks + 3], ac3, 0, 0, 0);
    }
    f32x4 acc = (ac0 + ac1) + (ac2 + ac3);

    float act[4];
    #pragma unroll
    for (int ri = 0; ri < 4; ++ri) {
      float v = acc[ri] + xpv[ri];
      act[ri] = (gate == 2) ? tanh_a(v) : sigm(v);
    }
    float hv[4];
    #pragma unroll
    for (int ri = 0; ri < 4; ++ri) {
      float iv = __shfl(act[ri], base);
      float fv = __shfl(act[ri], base + 4);
      float gv = __shfl(act[ri], base + 8);
      float ov = __shfl(act[ri], base + 12);
      cst[ri] = fv * cst[ri] + iv * gv;
      hv[ri] = ov * tanh_a(cst[ri]);
    }

    if (t == 511) {
      if (gate == 0) {
        #pragma unroll
        for (int ri = 0; ri < 4; ++ri) {
          int b = r0 + hi * 4 + ri;
          out[b * 1024 + hcol] = hv[ri];
          out[65536 + b * 1024 + hcol] = cst[ri];
        }
      }
      break;
    }

    // --- pack 4 cols -> one 8B atomic store per (hi,ri) row
    unsigned short* hn = hbuf + ((t + 1) & 1) * 65536;
    #pragma unroll
    for (int ri = 0; ri < 4; ++ri) {
      int hbv = (int)f2bf(hv[ri]);
      int c0 = __shfl(hbv, pbase + 0);
      int c1 = __shfl(hbv, pbase + 1);
      int c2 = __shfl(hbv, pbase + 2);
      int c3 = __shfl(hbv, pbase + 3);
      if (l15 == 0) {
        unsigned lo = ((unsigned)c0 & 0xFFFFu) | ((unsigned)c1 << 16);
        unsigned long long hi64 = ((unsigned)c2 & 0xFFFFu) | ((unsigned)c3 << 16);
        unsigned long long pv = (unsigned long long)lo | (hi64 << 32);
        int row = r0 + hi * 4 + ri;
        ASTORE((unsigned long long*)(hn + row * 1024 + 32 * cg + 4 * w), pv);
      }
    }

    // --- publish: syncthreads drains all waves' stores (vmcnt 0), then flag
    __syncthreads();
    if (tid == 0) ASTORE(flags + bid, (unsigned)(t + 1));

    // --- prefetch next step's xp under the poll shadow: strip flag, then 8B sc-load
    while (ALOAD(xflags + (t + 1) * 32 + cg) == 0) {}
    asm volatile("global_load_dwordx2 %0, %1, off sc0 sc1"
                 : "=v"(nf)
                 : "v"((const char*)xp + (((size_t)(t + 1) * 4096 + pc) * 64 + r0 + hi * 4) * 2)
                 : "memory");

    // --- wait: every wave polls this group's 32 h-flags (one 4B load/lane)
    {
      const unsigned int* fp = flags + q * 32 + (lane & 31);
      unsigned tgt = (unsigned)(t + 1);
      while (true) {
        unsigned f = ALOAD(fp);
        if (__all(f >= tgt)) break;
      }
    }
    asm volatile("s_waitcnt vmcnt(0)" ::: "memory");
    __builtin_amdgcn_sched_barrier(0);
    xpv[0] = bf2f((unsigned short)(nf.x & 0xFFFFu));
    xpv[1] = bf2f((unsigned short)(nf.x >> 16));
    xpv[2] = bf2f((unsigned short)(nf.y & 0xFFFFu));
    xpv[3] = bf2f((unsigned short)(nf.y >> 16));
  }
}

// ---------------- host ----------------

extern "C" void kernel_launch(void* const* d_in, const int* in_sizes, int n_in,
                              void* d_out, int out_size, void* d_ws, size_t ws_size,
                              hipStream_t stream) {
  const float* x = (const float*)d_in[0];
  const float* wxi = (const float*)d_in[1];
  const float* whi = (const float*)d_in[2];
  const float* wxf = (const float*)d_in[3];
  const float* whf = (const float*)d_in[4];
  const float* wxg = (const float*)d_in[5];
  const float* whg = (const float*)d_in[6];
  const float* wxo = (const float*)d_in[7];
  const float* who = (const float*)d_in[8];

  char* ws = (char*)d_ws;
  unsigned short* xbt   = (unsigned short*)(ws);                    // 64 MiB [t][b][1024]
  unsigned short* wxtp  = (unsigned short*)(ws + 67108864);         // 8 MiB
  unsigned short* whp   = (unsigned short*)(ws + 75497472);         // 8 MiB
  unsigned short* xpj   = (unsigned short*)(ws + 83886080);         // 256 MiB [t][pc][b]
  float*          pbx4  = (float*)(ws + 352321536);                 // 16 KiB
  unsigned short* hbuf  = (unsigned short*)(ws + 352337920);        // 256 KiB
  unsigned int*   flags = (unsigned int*)(ws + 352600064);          // 512 B
  unsigned int*   xflags= (unsigned int*)(ws + 352604160);          // 64 KiB

  k_cvt_x<<<16384, 256, 0, stream>>>(x, xbt);
  k_pack_w<<<dim3(32, 32, 8), dim3(32, 8), 0, stream>>>(wxi, wxf, wxg, wxo, whi, whf, whg, who, wxtp, whp);
  k_bias<<<16, 256, 0, stream>>>((const float*)d_in[9], (const float*)d_in[10],
                                 (const float*)d_in[11], (const float*)d_in[12],
                                 (const float*)d_in[13], (const float*)d_in[14],
                                 (const float*)d_in[15], (const float*)d_in[16], pbx4);
  k_init<<<128, 256, 0, stream>>>(hbuf, flags, xflags);

  float* out = (float*)d_out;
  void* args[] = {(void*)&xbt, (void*)&wxtp, (void*)&whp, (void*)&pbx4,
                  (void*)&xpj, (void*)&hbuf, (void*)&flags, (void*)&xflags, (void*)&out};
  hipLaunchCooperativeKernel((const void*)k_fused, dim3(256), dim3(512), args, 0, stream);
}